// Round 3
// baseline (1469.875 us; speedup 1.0000x reference)
//
#include <hip/hip_runtime.h>
#include <math.h>

// ---------------------------------------------------------------------------
// V=4096, READ_F=24, INFO_F=10, REF_LEN=25, CONV_C=32, KERN=3
// READ_E=128, INFO_E=64, SEQ_E=64, EMB=256, FFN=512, BLOCKS=2
// x (per-read activations) kept in bf16 everywhere; epilogue math in fp32.
// ---------------------------------------------------------------------------

typedef short short8 __attribute__((ext_vector_type(8)));
typedef __bf16 bf16x8 __attribute__((ext_vector_type(8)));
typedef float f32x4 __attribute__((ext_vector_type(4)));

__device__ inline unsigned short f2bf(float f) {
    unsigned u = __builtin_bit_cast(unsigned, f);
    u += 0x7fffu + ((u >> 16) & 1u);   // RNE
    return (unsigned short)(u >> 16);
}
__device__ inline float bf2f(unsigned short u) {
    unsigned v = ((unsigned)u) << 16;
    return __builtin_bit_cast(float, v);
}

__device__ inline f32x4 mfma16(short8 a, short8 b, f32x4 c) {
    return __builtin_amdgcn_mfma_f32_16x16x32_bf16(
        __builtin_bit_cast(bf16x8, a), __builtin_bit_cast(bf16x8, b), c, 0, 0, 0);
}

// XOR-swizzled LDS element index: byte = 2k ^ ((row&mask)<<4)  (16B granule)
__device__ inline int lds_idx(int row, int k, int Kp, int mask) {
    int b = (k << 1) ^ ((row & mask) << 4);
    return row * Kp + (b >> 1);
}

// ---------------- scan of counts -> exclusive offsets ----------------------
__global__ __launch_bounds__(256) void scan_counts(const int* __restrict__ cnt,
                                                   int* __restrict__ off, int V) {
    __shared__ int part[256];
    int t = threadIdx.x;
    int items = (V + 255) >> 8;
    int base = t * items;
    int s = 0;
    for (int i = 0; i < items; i++) {
        int idx = base + i;
        if (idx < V) s += cnt[idx];
    }
    part[t] = s;
    __syncthreads();
    for (int d = 1; d < 256; d <<= 1) {
        int v = (t >= d) ? part[t - d] : 0;
        __syncthreads();
        part[t] += v;
        __syncthreads();
    }
    int run = (t == 0) ? 0 : part[t - 1];
    for (int i = 0; i < items; i++) {
        int idx = base + i;
        if (idx < V) {
            off[idx] = run;
            run += cnt[idx];
        }
    }
    if (t == 255) off[V] = part[255];
}

__global__ void fill_ids(const int* __restrict__ off_r, int* __restrict__ rid_r,
                         const int* __restrict__ off_a, int* __restrict__ rid_a, int V) {
    int v = blockIdx.x * blockDim.x + threadIdx.x;
    if (v < V) {
        int s = off_r[v], e = off_r[v + 1];
        for (int r = s; r < e; r++) rid_r[r] = v;
    } else if (v < 2 * V) {
        int u = v - V;
        int s = off_a[u], e = off_a[u + 1];
        for (int r = s; r < e; r++) rid_a[r] = u;
    }
}

// ---------------- fp32 [K][N] -> bf16 [N][Kp] transpose (zero-padded K) ----
__global__ void transpose_bf16(const float* __restrict__ src, unsigned short* __restrict__ dst,
                               int K, int N, int Kp) {
    int idx = blockIdx.x * 256 + threadIdx.x;
    if (idx >= N * Kp) return;
    int n = idx / Kp, k = idx - n * Kp;
    dst[idx] = (k < K) ? f2bf(src[(size_t)k * N + n]) : (unsigned short)0;
}

__global__ void reads_to_bf(const float* __restrict__ reads, unsigned short* __restrict__ out,
                            int R) {
    int idx = blockIdx.x * 256 + threadIdx.x;
    if (idx >= R * 32) return;
    int r = idx >> 5, k = idx & 31;
    out[idx] = (k < 24) ? f2bf(reads[(size_t)r * 24 + k]) : (unsigned short)0;
}

// ---------------- generic MFMA GEMM: C = epi(A[M,K] @ Bt[N,K]^T + bias) ----
// EPI: 0 fp32, 1 relu->bf16, 2 sigmoid->fp32, 3 bf16 split ref/alt
template <int EPI>
__global__ __launch_bounds__(256, 4) void gemm_bf16(
        const unsigned short* __restrict__ A, const unsigned short* __restrict__ Bt,
        const float* __restrict__ bias, void* __restrict__ C0, void* __restrict__ C1,
        int M, int K, int mask, int ldc, int TR) {
    extern __shared__ unsigned short As[];
    const int m0 = blockIdx.x * 64, n0 = blockIdx.y * 64;
    const int tid = threadIdx.x;
    const int kc = K >> 3;
    for (int i = tid; i < (kc << 6); i += 256) {
        int r = i / kc, k8 = (i - r * kc) << 3;
        short8 v = {0, 0, 0, 0, 0, 0, 0, 0};
        if (m0 + r < M) v = *(const short8*)(A + (size_t)(m0 + r) * K + k8);
        *(short8*)&As[lds_idx(r, k8, K, mask)] = v;
    }
    __syncthreads();
    const int wid = tid >> 6, lane = tid & 63;
    const int lr = lane & 15, lg = lane >> 4;
    f32x4 acc[4];
#pragma unroll
    for (int ct = 0; ct < 4; ++ct) acc[ct] = f32x4{0.f, 0.f, 0.f, 0.f};
    const unsigned short* Bb = Bt + (size_t)(n0 + lr) * K + (lg << 3);
    const int nk = K >> 5;
    for (int s = 0; s < nk; ++s) {
        int k0 = (s << 5) + (lg << 3);
        short8 af = *(const short8*)&As[lds_idx((wid << 4) + lr, k0, K, mask)];
#pragma unroll
        for (int ct = 0; ct < 4; ++ct) {
            short8 bf = *(const short8*)(Bb + (size_t)(ct << 4) * K + (s << 5));
            acc[ct] = mfma16(af, bf, acc[ct]);
        }
    }
#pragma unroll
    for (int ct = 0; ct < 4; ++ct) {
        int c = n0 + (ct << 4) + lr;
        float bb = bias[c];
#pragma unroll
        for (int q = 0; q < 4; ++q) {
            int rg = m0 + (wid << 4) + (lg << 2) + q;
            if (rg >= M) continue;
            float v = acc[ct][q] + bb;
            if (EPI == 0) {
                ((float*)C0)[(size_t)rg * ldc + c] = v;
            } else if (EPI == 1) {
                ((unsigned short*)C0)[(size_t)rg * ldc + c] = f2bf(fmaxf(v, 0.f));
            } else if (EPI == 2) {
                ((float*)C0)[(size_t)rg * ldc + c] = 1.f / (1.f + __expf(-v));
            } else {
                unsigned short* base = (rg < TR) ? ((unsigned short*)C0 + (size_t)rg * ldc)
                                                 : ((unsigned short*)C1 + (size_t)(rg - TR) * ldc);
                base[c] = f2bf(v);
            }
        }
    }
}

// ---------------- per-variant info MLP + conv + seq linear -> isv bf16 -----
__global__ __launch_bounds__(128) void variant_embed(
        const float* __restrict__ info2d, const float* __restrict__ oh,
        const float* __restrict__ iw1, const float* __restrict__ ib1,
        const float* __restrict__ iw2, const float* __restrict__ ib2,
        const float* __restrict__ cw, const float* __restrict__ cb,
        const float* __restrict__ sw, const float* __restrict__ sb,
        unsigned short* __restrict__ isv, int V) {
    __shared__ float iw1s[10 * 64], iw2s[64 * 64], ib1s[64], ib2s[64];
    __shared__ float cws[32 * 4 * 3], cbs[32];
    __shared__ float ohs[100], cv[736], his[64], infs[10];
    int v = blockIdx.x;
    int t = threadIdx.x;
    for (int i = t; i < 640; i += 128) iw1s[i] = iw1[i];
    for (int i = t; i < 4096; i += 128) iw2s[i] = iw2[i];
    for (int i = t; i < 384; i += 128) cws[i] = cw[i];
    if (t < 64) { ib1s[t] = ib1[t]; ib2s[t] = ib2[t]; }
    if (t < 32) cbs[t] = cb[t];
    for (int i = t; i < 100; i += 128) ohs[i] = oh[(size_t)v * 100 + i];
    if (t < 10) infs[t] = info2d[(size_t)v * 10 + t];
    __syncthreads();
    for (int j = t; j < 736; j += 128) {
        int c = j / 23, p = j - c * 23;
        float a = cbs[c];
#pragma unroll
        for (int i = 0; i < 4; i++)
#pragma unroll
            for (int k = 0; k < 3; k++)
                a += cws[(c * 4 + i) * 3 + k] * ohs[i * 25 + p + k];
        cv[j] = fmaxf(a, 0.f);
    }
    if (t < 64) {
        float h = ib1s[t];
#pragma unroll
        for (int k = 0; k < 10; k++) h += infs[k] * iw1s[k * 64 + t];
        his[t] = fmaxf(h, 0.f);
    }
    __syncthreads();
    if (t < 64) {
        float o = ib2s[t];
        for (int k = 0; k < 64; k++) o += his[k] * iw2s[k * 64 + t];
        isv[(size_t)v * 128 + t] = f2bf(o);
    } else {
        int tt = t - 64;
        float s = sb[tt];
        for (int j = 0; j < 736; j++) s += cv[j] * sw[j * 64 + tt];
        isv[(size_t)v * 128 + 64 + tt] = f2bf(s);
    }
}

// ---------------- gather isv rows into x[:,128:256] (bf16, 16B chunks) -----
__global__ void gather_isv_bf(const uint4* __restrict__ isv4,
                              const int* __restrict__ rid_r, const int* __restrict__ rid_a,
                              uint4* __restrict__ xref4, uint4* __restrict__ xalt4,
                              int TR, int TA) {
    long idx = (long)blockIdx.x * blockDim.x + threadIdx.x;
    long total = (long)(TR + TA) * 16;
    if (idx >= total) return;
    int r = (int)(idx >> 4);
    int j = (int)(idx & 15);
    if (r < TR)
        xref4[(size_t)r * 32 + 16 + j] = isv4[(size_t)rid_r[r] * 16 + j];
    else {
        int r2 = r - TR;
        xalt4[(size_t)r2 * 32 + 16 + j] = isv4[(size_t)rid_a[r2] * 16 + j];
    }
}

// ---------------- segment means (bf16 in/out), stacked [alt; ref] ----------
// m2[0:V]   = alt_mean  (gates ref rows)
// m2[V:2V]  = ref_mean  (gates alt rows)
__global__ __launch_bounds__(256) void seg_mean_bf(
        const unsigned short* __restrict__ xref, const int* __restrict__ off_r,
        const unsigned short* __restrict__ xalt, const int* __restrict__ off_a,
        unsigned short* __restrict__ m2, int V) {
    int b = blockIdx.x;
    int t = threadIdx.x;
    const unsigned short* x;
    const int* off;
    unsigned short* out;
    int v;
    if (b < V) { x = xref; off = off_r; out = m2 + (size_t)(V + b) * 256; v = b; }
    else { x = xalt; off = off_a; out = m2 + (size_t)(b - V) * 256; v = b - V; }
    int s = off[v], e = off[v + 1];
    float acc = 0.f;
    for (int r = s; r < e; r++) acc += bf2f(x[(size_t)r * 256 + t]);
    out[t] = f2bf(acc / (float)(e - s));
}

// ---------------- fused gated residual block (32-row tile, 8 waves) --------
// GEMM1 swapped: HT = W1t(A) x X(B)  -> lane owns x-row m=lane&15
// GEMM2 standard: O  = Hs(A) x W2t(B)
__global__ __launch_bounds__(512, 4) void fused_block(
        unsigned short* __restrict__ xref, unsigned short* __restrict__ xalt,
        const unsigned short* __restrict__ W1t,   // [512][256]
        const unsigned short* __restrict__ W2t,   // [256][512]
        const float* __restrict__ b1, const float* __restrict__ b2,
        const float* __restrict__ gate_r, const float* __restrict__ gate_a,
        const int* __restrict__ rid_r, const int* __restrict__ rid_a,
        int TR, int TA, int ntr) {
    __shared__ unsigned short Xs[32 * 256];   // swizzled bf16 x tile
    __shared__ unsigned short Hs[32 * 512];   // swizzled bf16 H tile / out restage
    __shared__ int rid_s[32];
    const int bid = blockIdx.x;
    const bool isref = bid < ntr;
    const int m0 = (isref ? bid : bid - ntr) * 32;
    const int M = isref ? TR : TA;
    unsigned short* x = isref ? xref : xalt;
    const float* gate = isref ? gate_r : gate_a;
    const int* rid = isref ? rid_r : rid_a;
    const int tid = threadIdx.x;
    if (tid < 32) rid_s[tid] = (m0 + tid < M) ? rid[m0 + tid] : 0;
    // ---- stage X: pre-swizzled source, linear LDS dest ----
    for (int i = tid; i < 32 * 32; i += 512) {
        int r = i >> 5, j = i & 31;            // row, 16B chunk
        short8 v = {0, 0, 0, 0, 0, 0, 0, 0};
        if (m0 + r < M)
            v = *(const short8*)(x + (size_t)(m0 + r) * 256 + ((j ^ (r & 7)) << 3));
        *(short8*)&Xs[r * 256 + (j << 3)] = v;
    }
    __syncthreads();
    const int wid = tid >> 6, lane = tid & 63;
    const int li = lane & 15, lg = lane >> 4;
    // ---- GEMM1 (swapped): wave (mi, ns) -> HT[n in ns..ns+127][m in mi*16..+15]
    const int mi = wid >> 2;                  // 0..1
    const int ns = (wid & 3) << 7;            // 0,128,256,384
    f32x4 acc1[8];
#pragma unroll
    for (int ct = 0; ct < 8; ++ct) acc1[ct] = f32x4{0.f, 0.f, 0.f, 0.f};
    const unsigned short* Ab = W1t + (size_t)(ns + li) * 256 + (lg << 3);
#pragma unroll
    for (int s = 0; s < 8; ++s) {             // K = 256
        int k0 = (s << 5) + (lg << 3);
        short8 bx = *(const short8*)&Xs[lds_idx((mi << 4) + li, k0, 256, 7)];
#pragma unroll
        for (int ct = 0; ct < 8; ++ct) {
            short8 aw = *(const short8*)(Ab + (size_t)(ct << 4) * 256 + (s << 5));
            acc1[ct] = mfma16(aw, bx, acc1[ct]);
        }
    }
    // ---- epilogue 1: relu * gate -> Hs (packed 8B writes) ----
    {
        const int m = (mi << 4) + li;                    // lane's x-row
        const float* grow = gate + (size_t)rid_s[m] * 512 + ns + (lg << 2);
        const float* b1p = b1 + ns + (lg << 2);
#pragma unroll
        for (int ct = 0; ct < 8; ++ct) {
            float4 gv = *(const float4*)(grow + (ct << 4));
            float4 bv = *(const float4*)(b1p + (ct << 4));
            unsigned short h0 = f2bf(fmaxf(acc1[ct][0] + bv.x, 0.f) * gv.x);
            unsigned short h1 = f2bf(fmaxf(acc1[ct][1] + bv.y, 0.f) * gv.y);
            unsigned short h2 = f2bf(fmaxf(acc1[ct][2] + bv.z, 0.f) * gv.z);
            unsigned short h3 = f2bf(fmaxf(acc1[ct][3] + bv.w, 0.f) * gv.w);
            uint2 pk;
            pk.x = (unsigned)h0 | ((unsigned)h1 << 16);
            pk.y = (unsigned)h2 | ((unsigned)h3 << 16);
            int n = ns + (ct << 4) + (lg << 2);
            *(uint2*)&Hs[lds_idx(m, n, 512, 7)] = pk;
        }
    }
    __syncthreads();
    // ---- GEMM2: wave (mi2, cs) -> O[mi2*16..+15][cs..cs+63], K = 512 ----
    const int mi2 = wid >> 2;
    const int cs = (wid & 3) << 6;
    f32x4 acc2[4];
#pragma unroll
    for (int ct = 0; ct < 4; ++ct) acc2[ct] = f32x4{0.f, 0.f, 0.f, 0.f};
    const unsigned short* Bb2 = W2t + (size_t)(cs + li) * 512 + (lg << 3);
#pragma unroll
    for (int s = 0; s < 16; ++s) {
        int k0 = (s << 5) + (lg << 3);
        short8 ah = *(const short8*)&Hs[lds_idx((mi2 << 4) + li, k0, 512, 7)];
#pragma unroll
        for (int ct = 0; ct < 4; ++ct) {
            short8 bw = *(const short8*)(Bb2 + (size_t)(ct << 4) * 512 + (s << 5));
            acc2[ct] = mfma16(ah, bw, acc2[ct]);
        }
    }
    // ---- epilogue 2: residual add (fp32 math) into registers ----
    unsigned short outv[4][4];
#pragma unroll
    for (int ct = 0; ct < 4; ++ct) {
        int c = cs + (ct << 4) + li;
        float bb = b2[c];
#pragma unroll
        for (int q = 0; q < 4; ++q) {
            int rl = (mi2 << 4) + (lg << 2) + q;
            float xo = bf2f(Xs[lds_idx(rl, c, 256, 7)]);
            outv[ct][q] = f2bf(xo + acc2[ct][q] + bb);
        }
    }
    __syncthreads();                           // all Hs reads done
    unsigned short* OutS = Hs;                 // reuse as [32][256] row-major
#pragma unroll
    for (int ct = 0; ct < 4; ++ct) {
        int c = cs + (ct << 4) + li;
#pragma unroll
        for (int q = 0; q < 4; ++q) {
            int rl = (mi2 << 4) + (lg << 2) + q;
            OutS[rl * 256 + c] = outv[ct][q];
        }
    }
    __syncthreads();
    // ---- coalesced global store ----
    for (int i = tid; i < 32 * 32; i += 512) {
        int r = i >> 5, j = i & 31;
        if (m0 + r < M)
            *(short8*)(x + (size_t)(m0 + r) * 256 + (j << 3)) = *(const short8*)&OutS[r * 256 + (j << 3)];
    }
}

// ---------------- weighted alt segment sums --------------------------------
__global__ void alt_wsum(const float* __restrict__ au, const int* __restrict__ off_a,
                         float* __restrict__ wsum, int V) {
    int v = blockIdx.x * blockDim.x + threadIdx.x;
    if (v >= V) return;
    float s = 0.f;
    for (int r = off_a[v]; r < off_a[v + 1]; r++) s += 1.2f - 0.4f * au[r];
    wsum[v] = s;
}

__global__ __launch_bounds__(256) void alt_weighted_mean_bf(
        const unsigned short* __restrict__ xalt, const float* __restrict__ au,
        const int* __restrict__ off_a, const float* __restrict__ wsum,
        unsigned short* __restrict__ av, int V) {
    int v = blockIdx.x;
    int t = threadIdx.x;
    int s = off_a[v], e = off_a[v + 1];
    float inv = 1.f / wsum[v];
    float acc = 0.f;
    for (int r = s; r < e; r++) {
        float w = (1.2f - 0.4f * au[r]) * inv;
        acc += bf2f(xalt[(size_t)r * 256 + t]) * w;
    }
    av[(size_t)v * 256 + t] = f2bf(acc);
}

// ---------------------------------------------------------------------------
extern "C" void kernel_launch(void* const* d_in, const int* in_sizes, int n_in,
                              void* d_out, int out_size, void* d_ws, size_t ws_size,
                              hipStream_t stream) {
    const float* reads = (const float*)d_in[0];
    const float* info2d = (const float*)d_in[1];
    const float* oh = (const float*)d_in[2];
    const float* au = (const float*)d_in[3];
    const int* ref_counts = (const int*)d_in[4];
    const int* alt_counts = (const int*)d_in[5];
    const float* rw1 = (const float*)d_in[6];
    const float* rb1 = (const float*)d_in[7];
    const float* rw2 = (const float*)d_in[8];
    const float* rb2 = (const float*)d_in[9];
    const float* iw1 = (const float*)d_in[10];
    const float* ib1 = (const float*)d_in[11];
    const float* iw2 = (const float*)d_in[12];
    const float* ib2 = (const float*)d_in[13];
    const float* cw = (const float*)d_in[14];
    const float* cb = (const float*)d_in[15];
    const float* sw = (const float*)d_in[16];
    const float* sb = (const float*)d_in[17];
    const float* blk_w1 = (const float*)d_in[18];
    const float* blk_b1 = (const float*)d_in[19];
    const float* blk_wg = (const float*)d_in[20];
    const float* blk_bg = (const float*)d_in[21];
    const float* blk_w2 = (const float*)d_in[22];
    const float* blk_b2 = (const float*)d_in[23];
    const float* agg_w1 = (const float*)d_in[24];
    const float* agg_b1 = (const float*)d_in[25];
    const float* agg_w2 = (const float*)d_in[26];
    const float* agg_b2 = (const float*)d_in[27];

    const int R = in_sizes[0] / 24;
    const int TA = in_sizes[3];
    const int TR = R - TA;
    const int V = in_sizes[4];

    size_t p = 0;
    auto carve = [&](size_t bytes) -> void* {
        void* q = (char*)d_ws + p;
        p = (p + bytes + 255) & ~(size_t)255;
        return q;
    };
    // persistent
    int* off_r = (int*)carve((V + 1) * sizeof(int));
    int* off_a = (int*)carve((V + 1) * sizeof(int));
    int* rid_r = (int*)carve((size_t)TR * sizeof(int));
    int* rid_a = (int*)carve((size_t)TA * sizeof(int));
    unsigned short* isv = (unsigned short*)carve((size_t)V * 128 * 2);
    unsigned short* xref = (unsigned short*)carve((size_t)TR * 256 * 2);
    unsigned short* xalt = (unsigned short*)carve((size_t)TA * 256 * 2);
    unsigned short* W1t0 = (unsigned short*)carve((size_t)512 * 256 * 2);
    unsigned short* W1t1 = (unsigned short*)carve((size_t)512 * 256 * 2);
    unsigned short* Wgt0 = (unsigned short*)carve((size_t)512 * 256 * 2);
    unsigned short* Wgt1 = (unsigned short*)carve((size_t)512 * 256 * 2);
    unsigned short* W2t0 = (unsigned short*)carve((size_t)256 * 512 * 2);
    unsigned short* W2t1 = (unsigned short*)carve((size_t)256 * 512 * 2);
    unsigned short* RW1t = (unsigned short*)carve((size_t)128 * 32 * 2);
    unsigned short* RW2t = (unsigned short*)carve((size_t)128 * 128 * 2);
    unsigned short* AG1t = (unsigned short*)carve((size_t)256 * 256 * 2);
    unsigned short* AG2t = (unsigned short*)carve((size_t)128 * 256 * 2);
    float* wsum = (float*)carve((size_t)V * sizeof(float));
    // union A: read path temporaries
    size_t mark = p;
    unsigned short* reads_bf = (unsigned short*)carve((size_t)R * 32 * 2);
    unsigned short* h1 = (unsigned short*)carve((size_t)R * 128 * 2);
    size_t endA = p;
    // union B: block loop / aggregation
    p = mark;
    unsigned short* m2 = (unsigned short*)carve((size_t)2 * V * 256 * 2);   // [alt;ref] means
    float* gate2 = (float*)carve((size_t)2 * V * 512 * sizeof(float));      // [gate_r;gate_a]
    unsigned short* avb_bf = (unsigned short*)carve((size_t)V * 256 * 2);
    unsigned short* aggh_bf = (unsigned short*)carve((size_t)V * 256 * 2);
    if (endA > p) p = endA;
    (void)ws_size; (void)n_in; (void)out_size;

    // ---- offsets / ids ----
    scan_counts<<<1, 256, 0, stream>>>(ref_counts, off_r, V);
    scan_counts<<<1, 256, 0, stream>>>(alt_counts, off_a, V);
    fill_ids<<<(2 * V + 255) / 256, 256, 0, stream>>>(off_r, rid_r, off_a, rid_a, V);

    // ---- weight transposes ----
    auto T = [&](const float* src, unsigned short* dst, int K, int N, int Kp) {
        int tot = N * Kp;
        transpose_bf16<<<(tot + 255) / 256, 256, 0, stream>>>(src, dst, K, N, Kp);
    };
    T(blk_w1, W1t0, 256, 512, 256);
    T(blk_w1 + 256 * 512, W1t1, 256, 512, 256);
    T(blk_wg, Wgt0, 256, 512, 256);
    T(blk_wg + 256 * 512, Wgt1, 256, 512, 256);
    T(blk_w2, W2t0, 512, 256, 512);
    T(blk_w2 + 512 * 256, W2t1, 512, 256, 512);
    T(rw1, RW1t, 24, 128, 32);
    T(rw2, RW2t, 128, 128, 128);
    T(agg_w1, AG1t, 256, 256, 256);
    T(agg_w2, AG2t, 256, 128, 256);

    // ---- read MLP -> x[:,0:128] (bf16) ----
    reads_to_bf<<<(R * 32 + 255) / 256, 256, 0, stream>>>(reads, reads_bf, R);
    {
        dim3 g1((R + 63) / 64, 2);
        gemm_bf16<1><<<g1, 256, 64 * 32 * 2, stream>>>(reads_bf, RW1t, rb1, h1, nullptr,
                                                       R, 32, 3, 128, 0);
        gemm_bf16<3><<<g1, 256, 64 * 128 * 2, stream>>>(h1, RW2t, rb2, xref, xalt,
                                                        R, 128, 7, 256, TR);
    }

    // ---- variant embeddings -> x[:,128:256] (bf16) ----
    variant_embed<<<V, 128, 0, stream>>>(info2d, oh, iw1, ib1, iw2, ib2, cw, cb, sw, sb, isv, V);
    long gtot = (long)R * 16;
    gather_isv_bf<<<(int)((gtot + 255) / 256), 256, 0, stream>>>(
        (const uint4*)isv, rid_r, rid_a, (uint4*)xref, (uint4*)xalt, TR, TA);

    // ---- 2 gated residual blocks ----
    const int ntr = (TR + 31) / 32, nta = (TA + 31) / 32;
    for (int it = 0; it < 2; ++it) {
        const unsigned short* W1t = it ? W1t1 : W1t0;
        const unsigned short* Wgt = it ? Wgt1 : Wgt0;
        const unsigned short* W2t = it ? W2t1 : W2t0;
        const float* B1 = blk_b1 + (size_t)it * 512;
        const float* Bg = blk_bg + (size_t)it * 512;
        const float* B2 = blk_b2 + (size_t)it * 256;

        seg_mean_bf<<<2 * V, 256, 0, stream>>>(xref, off_r, xalt, off_a, m2, V);
        // one stacked gate GEMM: rows [0,V)=gate_r (from alt means), [V,2V)=gate_a
        dim3 gg(2 * V / 64, 8);
        gemm_bf16<2><<<gg, 256, 64 * 256 * 2, stream>>>(m2, Wgt, Bg, gate2, nullptr,
                                                        2 * V, 256, 7, 512, 0);
        fused_block<<<ntr + nta, 512, 0, stream>>>(xref, xalt, W1t, W2t, B1, B2,
                                                   gate2, gate2 + (size_t)V * 512,
                                                   rid_r, rid_a, TR, TA, ntr);
    }

    // ---- weighted alt means + agg MLP ----
    alt_wsum<<<(V + 255) / 256, 256, 0, stream>>>(au, off_a, wsum, V);
    alt_weighted_mean_bf<<<V, 256, 0, stream>>>(xalt, au, off_a, wsum, avb_bf, V);
    {
        dim3 ga(V / 64, 4);
        gemm_bf16<1><<<ga, 256, 64 * 256 * 2, stream>>>(avb_bf, AG1t, agg_b1, aggh_bf, nullptr,
                                                        V, 256, 7, 256, 0);
        dim3 go(V / 64, 2);
        gemm_bf16<0><<<go, 256, 64 * 256 * 2, stream>>>(aggh_bf, AG2t, agg_b2, d_out, nullptr,
                                                        V, 256, 7, 128, 0);
    }
}

// Round 4
// 713.202 us; speedup vs baseline: 2.0610x; 2.0610x over previous
//
#include <hip/hip_runtime.h>
#include <math.h>

// ---------------------------------------------------------------------------
// V=4096, READ_F=24, INFO_F=10, REF_LEN=25, CONV_C=32, KERN=3
// READ_E=128, INFO_E=64, SEQ_E=64, EMB=256, FFN=512, BLOCKS=2
// x (per-read activations) kept in bf16 everywhere; epilogue math in fp32.
// ---------------------------------------------------------------------------

typedef short short8 __attribute__((ext_vector_type(8)));
typedef __bf16 bf16x8 __attribute__((ext_vector_type(8)));
typedef float f32x4 __attribute__((ext_vector_type(4)));

__device__ inline unsigned short f2bf(float f) {
    unsigned u = __builtin_bit_cast(unsigned, f);
    u += 0x7fffu + ((u >> 16) & 1u);   // RNE
    return (unsigned short)(u >> 16);
}
__device__ inline float bf2f(unsigned short u) {
    unsigned v = ((unsigned)u) << 16;
    return __builtin_bit_cast(float, v);
}

__device__ inline f32x4 mfma16(short8 a, short8 b, f32x4 c) {
    return __builtin_amdgcn_mfma_f32_16x16x32_bf16(
        __builtin_bit_cast(bf16x8, a), __builtin_bit_cast(bf16x8, b), c, 0, 0, 0);
}

// XOR-swizzled LDS element index (16B granule): elem = k ^ ((row&mask)<<3)
__device__ inline int lds_idx(int row, int k, int Kp, int mask) {
    return row * Kp + (k ^ ((row & mask) << 3));
}

// ---------------- scan of counts -> exclusive offsets ----------------------
__global__ __launch_bounds__(256) void scan_counts(const int* __restrict__ cnt,
                                                   int* __restrict__ off, int V) {
    __shared__ int part[256];
    int t = threadIdx.x;
    int items = (V + 255) >> 8;
    int base = t * items;
    int s = 0;
    for (int i = 0; i < items; i++) {
        int idx = base + i;
        if (idx < V) s += cnt[idx];
    }
    part[t] = s;
    __syncthreads();
    for (int d = 1; d < 256; d <<= 1) {
        int v = (t >= d) ? part[t - d] : 0;
        __syncthreads();
        part[t] += v;
        __syncthreads();
    }
    int run = (t == 0) ? 0 : part[t - 1];
    for (int i = 0; i < items; i++) {
        int idx = base + i;
        if (idx < V) {
            off[idx] = run;
            run += cnt[idx];
        }
    }
    if (t == 255) off[V] = part[255];
}

__global__ void fill_ids(const int* __restrict__ off_r, int* __restrict__ rid_r,
                         const int* __restrict__ off_a, int* __restrict__ rid_a, int V) {
    int v = blockIdx.x * blockDim.x + threadIdx.x;
    if (v < V) {
        int s = off_r[v], e = off_r[v + 1];
        for (int r = s; r < e; r++) rid_r[r] = v;
    } else if (v < 2 * V) {
        int u = v - V;
        int s = off_a[u], e = off_a[u + 1];
        for (int r = s; r < e; r++) rid_a[r] = u;
    }
}

// ---------------- fp32 [K][N] -> bf16 [N][Kp] transpose (zero-padded K) ----
__global__ void transpose_bf16(const float* __restrict__ src, unsigned short* __restrict__ dst,
                               int K, int N, int Kp) {
    int idx = blockIdx.x * 256 + threadIdx.x;
    if (idx >= N * Kp) return;
    int n = idx / Kp, k = idx - n * Kp;
    dst[idx] = (k < K) ? f2bf(src[(size_t)k * N + n]) : (unsigned short)0;
}

__global__ void reads_to_bf(const float* __restrict__ reads, unsigned short* __restrict__ out,
                            int R) {
    int idx = blockIdx.x * 256 + threadIdx.x;
    if (idx >= R * 32) return;
    int r = idx >> 5, k = idx & 31;
    out[idx] = (k < 24) ? f2bf(reads[(size_t)r * 24 + k]) : (unsigned short)0;
}

// ---------------- generic MFMA GEMM: C = epi(A[M,K] @ Bt[N,K]^T + bias) ----
// EPI: 0 fp32, 1 relu->bf16, 2 sigmoid->fp32, 3 bf16 split ref/alt
template <int EPI>
__global__ __launch_bounds__(256, 4) void gemm_bf16(
        const unsigned short* __restrict__ A, const unsigned short* __restrict__ Bt,
        const float* __restrict__ bias, void* __restrict__ C0, void* __restrict__ C1,
        int M, int K, int mask, int ldc, int TR) {
    extern __shared__ unsigned short As[];
    const int m0 = blockIdx.x * 64, n0 = blockIdx.y * 64;
    const int tid = threadIdx.x;
    const int kc = K >> 3;
    for (int i = tid; i < (kc << 6); i += 256) {
        int r = i / kc, k8 = (i - r * kc) << 3;
        short8 v = {0, 0, 0, 0, 0, 0, 0, 0};
        if (m0 + r < M) v = *(const short8*)(A + (size_t)(m0 + r) * K + k8);
        *(short8*)&As[lds_idx(r, k8, K, mask)] = v;
    }
    __syncthreads();
    const int wid = tid >> 6, lane = tid & 63;
    const int lr = lane & 15, lg = lane >> 4;
    f32x4 acc[4];
#pragma unroll
    for (int ct = 0; ct < 4; ++ct) acc[ct] = f32x4{0.f, 0.f, 0.f, 0.f};
    const unsigned short* Bb = Bt + (size_t)(n0 + lr) * K + (lg << 3);
    const int nk = K >> 5;
    for (int s = 0; s < nk; ++s) {
        int k0 = (s << 5) + (lg << 3);
        short8 af = *(const short8*)&As[lds_idx((wid << 4) + lr, k0, K, mask)];
#pragma unroll
        for (int ct = 0; ct < 4; ++ct) {
            short8 bf = *(const short8*)(Bb + (size_t)(ct << 4) * K + (s << 5));
            acc[ct] = mfma16(af, bf, acc[ct]);
        }
    }
#pragma unroll
    for (int ct = 0; ct < 4; ++ct) {
        int c = n0 + (ct << 4) + lr;
        float bb = bias[c];
#pragma unroll
        for (int q = 0; q < 4; ++q) {
            int rg = m0 + (wid << 4) + (lg << 2) + q;
            if (rg >= M) continue;
            float v = acc[ct][q] + bb;
            if (EPI == 0) {
                ((float*)C0)[(size_t)rg * ldc + c] = v;
            } else if (EPI == 1) {
                ((unsigned short*)C0)[(size_t)rg * ldc + c] = f2bf(fmaxf(v, 0.f));
            } else if (EPI == 2) {
                ((float*)C0)[(size_t)rg * ldc + c] = 1.f / (1.f + __expf(-v));
            } else {
                unsigned short* base = (rg < TR) ? ((unsigned short*)C0 + (size_t)rg * ldc)
                                                 : ((unsigned short*)C1 + (size_t)(rg - TR) * ldc);
                base[c] = f2bf(v);
            }
        }
    }
}

// ---------------- per-variant info MLP + conv + seq linear -> isv bf16 -----
__global__ __launch_bounds__(128) void variant_embed(
        const float* __restrict__ info2d, const float* __restrict__ oh,
        const float* __restrict__ iw1, const float* __restrict__ ib1,
        const float* __restrict__ iw2, const float* __restrict__ ib2,
        const float* __restrict__ cw, const float* __restrict__ cb,
        const float* __restrict__ sw, const float* __restrict__ sb,
        unsigned short* __restrict__ isv, int V) {
    __shared__ float iw1s[10 * 64], iw2s[64 * 64], ib1s[64], ib2s[64];
    __shared__ float cws[32 * 4 * 3], cbs[32];
    __shared__ float ohs[100], cv[736], his[64], infs[10];
    int v = blockIdx.x;
    int t = threadIdx.x;
    for (int i = t; i < 640; i += 128) iw1s[i] = iw1[i];
    for (int i = t; i < 4096; i += 128) iw2s[i] = iw2[i];
    for (int i = t; i < 384; i += 128) cws[i] = cw[i];
    if (t < 64) { ib1s[t] = ib1[t]; ib2s[t] = ib2[t]; }
    if (t < 32) cbs[t] = cb[t];
    for (int i = t; i < 100; i += 128) ohs[i] = oh[(size_t)v * 100 + i];
    if (t < 10) infs[t] = info2d[(size_t)v * 10 + t];
    __syncthreads();
    for (int j = t; j < 736; j += 128) {
        int c = j / 23, p = j - c * 23;
        float a = cbs[c];
#pragma unroll
        for (int i = 0; i < 4; i++)
#pragma unroll
            for (int k = 0; k < 3; k++)
                a += cws[(c * 4 + i) * 3 + k] * ohs[i * 25 + p + k];
        cv[j] = fmaxf(a, 0.f);
    }
    if (t < 64) {
        float h = ib1s[t];
#pragma unroll
        for (int k = 0; k < 10; k++) h += infs[k] * iw1s[k * 64 + t];
        his[t] = fmaxf(h, 0.f);
    }
    __syncthreads();
    if (t < 64) {
        float o = ib2s[t];
        for (int k = 0; k < 64; k++) o += his[k] * iw2s[k * 64 + t];
        isv[(size_t)v * 128 + t] = f2bf(o);
    } else {
        int tt = t - 64;
        float s = sb[tt];
        for (int j = 0; j < 736; j++) s += cv[j] * sw[j * 64 + tt];
        isv[(size_t)v * 128 + 64 + tt] = f2bf(s);
    }
}

// ---------------- gather isv rows into x[:,128:256] (bf16, 16B chunks) -----
__global__ void gather_isv_bf(const uint4* __restrict__ isv4,
                              const int* __restrict__ rid_r, const int* __restrict__ rid_a,
                              uint4* __restrict__ xref4, uint4* __restrict__ xalt4,
                              int TR, int TA) {
    long idx = (long)blockIdx.x * blockDim.x + threadIdx.x;
    long total = (long)(TR + TA) * 16;
    if (idx >= total) return;
    int r = (int)(idx >> 4);
    int j = (int)(idx & 15);
    if (r < TR)
        xref4[(size_t)r * 32 + 16 + j] = isv4[(size_t)rid_r[r] * 16 + j];
    else {
        int r2 = r - TR;
        xalt4[(size_t)r2 * 32 + 16 + j] = isv4[(size_t)rid_a[r2] * 16 + j];
    }
}

// ---------------- segment means (bf16 in/out, vectorized), stacked --------
// m2[0:V] = alt_mean (gates ref rows) ; m2[V:2V] = ref_mean (gates alt rows)
__global__ __launch_bounds__(256) void seg_mean_bf(
        const unsigned short* __restrict__ xref, const int* __restrict__ off_r,
        const unsigned short* __restrict__ xalt, const int* __restrict__ off_a,
        unsigned short* __restrict__ m2, int V) {
    __shared__ float red[2048];
    int b = blockIdx.x;
    int t = threadIdx.x;
    const unsigned short* x;
    const int* off;
    unsigned short* out;
    int v;
    if (b < V) { x = xref; off = off_r; out = m2 + (size_t)(V + b) * 256; v = b; }
    else { x = xalt; off = off_a; out = m2 + (size_t)(b - V) * 256; v = b - V; }
    int s = off[v], e = off[v + 1];
    int g = t >> 5, c8 = (t & 31) << 3;
    float a[8] = {0.f, 0.f, 0.f, 0.f, 0.f, 0.f, 0.f, 0.f};
    for (int r = s + g; r < e; r += 8) {
        short8 vv = *(const short8*)(x + (size_t)r * 256 + c8);
#pragma unroll
        for (int k = 0; k < 8; k++) a[k] += bf2f((unsigned short)vv[k]);
    }
#pragma unroll
    for (int k = 0; k < 8; k++) red[g * 256 + c8 + k] = a[k];
    __syncthreads();
    float acc = red[t];
#pragma unroll
    for (int g2 = 1; g2 < 8; g2++) acc += red[g2 * 256 + t];
    out[t] = f2bf(acc / (float)(e - s));
}

// ---------------- fused gated residual block (64-row tile, 8 waves) --------
// Phases: stage Xs -> GEMM1 (swapped: H^T layout, packed gate+Hs writes)
//         -> Hs -> GEMM2 -> OutF(f32) -> coalesced store with residual.
// LDS: one 64KB union (Xs 32KB / Hs 64KB / OutF 64KB), 2 blocks/CU.
__global__ __launch_bounds__(512, 4) void fused_block(
        unsigned short* __restrict__ xref, unsigned short* __restrict__ xalt,
        const unsigned short* __restrict__ W1t,   // [512][256]
        const unsigned short* __restrict__ W2t,   // [256][512]
        const float* __restrict__ b1, const float* __restrict__ b2,
        const float* __restrict__ gate_r, const float* __restrict__ gate_a,
        const int* __restrict__ rid_r, const int* __restrict__ rid_a,
        int TR, int TA, int ntr) {
    __shared__ unsigned short U[64 * 512];        // 64 KB union
    __shared__ int rid_s[64];
    float* OutF = (float*)U;
    const int bid = blockIdx.x;
    const bool isref = bid < ntr;
    const int m0 = (isref ? bid : bid - ntr) * 64;
    const int M = isref ? TR : TA;
    unsigned short* x = isref ? xref : xalt;
    const float* gate = isref ? gate_r : gate_a;
    const int* rid = isref ? rid_r : rid_a;
    const int tid = threadIdx.x;
    if (tid < 64) rid_s[tid] = (m0 + tid < M) ? rid[m0 + tid] : 0;
    // ---- stage X (pre-swizzled source, linear LDS dest): Xs = U[0..16K elems)
    for (int i = tid; i < 64 * 32; i += 512) {
        int r = i >> 5, j = i & 31;
        short8 v = {0, 0, 0, 0, 0, 0, 0, 0};
        if (m0 + r < M)
            v = *(const short8*)(x + (size_t)(m0 + r) * 256 + ((j ^ (r & 15)) << 3));
        *(short8*)&U[r * 256 + (j << 3)] = v;
    }
    __syncthreads();
    const int wid = tid >> 6, lane = tid & 63;
    const int li = lane & 15, lg = lane >> 4;
    // ---- GEMM1 (swapped): wave owns 64-col strip ns; acc1[rt][ct] holds
    //      H[m=rt*16+li][n=ns+ct*16+lg*4+q]. Weights reg-double-buffered.
    const int ns = wid << 6;
    f32x4 acc1[4][4];
#pragma unroll
    for (int i = 0; i < 4; ++i)
#pragma unroll
        for (int j = 0; j < 4; ++j) acc1[i][j] = f32x4{0.f, 0.f, 0.f, 0.f};
    const unsigned short* Ap = W1t + (size_t)(ns + li) * 256 + (lg << 3);
    short8 awc[4], awn[4];
#pragma unroll
    for (int ct = 0; ct < 4; ++ct) awc[ct] = *(const short8*)(Ap + ct * 4096);
#pragma unroll
    for (int s = 0; s < 8; ++s) {
        if (s < 7) {
#pragma unroll
            for (int ct = 0; ct < 4; ++ct)
                awn[ct] = *(const short8*)(Ap + ct * 4096 + ((s + 1) << 5));
        }
        int k0 = (s << 5) + (lg << 3);
        short8 bx[4];
#pragma unroll
        for (int rt = 0; rt < 4; ++rt)
            bx[rt] = *(const short8*)&U[lds_idx(rt * 16 + li, k0, 256, 15)];
        __builtin_amdgcn_s_setprio(1);
#pragma unroll
        for (int rt = 0; rt < 4; ++rt)
#pragma unroll
            for (int ct = 0; ct < 4; ++ct)
                acc1[rt][ct] = mfma16(awc[ct], bx[rt], acc1[rt][ct]);
        __builtin_amdgcn_s_setprio(0);
#pragma unroll
        for (int ct = 0; ct < 4; ++ct) awc[ct] = awn[ct];
    }
    __syncthreads();                              // Xs dead; U becomes Hs
    // ---- epilogue 1: relu*gate -> Hs (packed 8B writes, float4 gate loads)
#pragma unroll
    for (int rt = 0; rt < 4; ++rt) {
        int m = rt * 16 + li;
        const float* grow = gate + (size_t)rid_s[m] * 512 + ns + (lg << 2);
        const float* b1p = b1 + ns + (lg << 2);
#pragma unroll
        for (int ct = 0; ct < 4; ++ct) {
            float4 gv = *(const float4*)(grow + (ct << 4));
            float4 bv = *(const float4*)(b1p + (ct << 4));
            unsigned h0 = f2bf(fmaxf(acc1[rt][ct][0] + bv.x, 0.f) * gv.x);
            unsigned h1 = f2bf(fmaxf(acc1[rt][ct][1] + bv.y, 0.f) * gv.y);
            unsigned h2 = f2bf(fmaxf(acc1[rt][ct][2] + bv.z, 0.f) * gv.z);
            unsigned h3 = f2bf(fmaxf(acc1[rt][ct][3] + bv.w, 0.f) * gv.w);
            uint2 pk;
            pk.x = h0 | (h1 << 16);
            pk.y = h2 | (h3 << 16);
            int n = ns + (ct << 4) + (lg << 2);
            *(uint2*)&U[lds_idx(m, n, 512, 15)] = pk;
        }
    }
    __syncthreads();
    // ---- GEMM2: wave owns 32-col strip cs; rows from Hs, W2t dbuf'd ----
    const int cs = wid << 5;
    f32x4 acc2[4][2];
#pragma unroll
    for (int i = 0; i < 4; ++i)
#pragma unroll
        for (int j = 0; j < 2; ++j) acc2[i][j] = f32x4{0.f, 0.f, 0.f, 0.f};
    const unsigned short* Bp = W2t + (size_t)(cs + li) * 512 + (lg << 3);
    short8 bwc[2], bwn[2];
#pragma unroll
    for (int ct = 0; ct < 2; ++ct) bwc[ct] = *(const short8*)(Bp + ct * 8192);
#pragma unroll
    for (int s = 0; s < 16; ++s) {
        if (s < 15) {
#pragma unroll
            for (int ct = 0; ct < 2; ++ct)
                bwn[ct] = *(const short8*)(Bp + ct * 8192 + ((s + 1) << 5));
        }
        int k0 = (s << 5) + (lg << 3);
        short8 ah[4];
#pragma unroll
        for (int rt = 0; rt < 4; ++rt)
            ah[rt] = *(const short8*)&U[lds_idx(rt * 16 + li, k0, 512, 15)];
        __builtin_amdgcn_s_setprio(1);
#pragma unroll
        for (int rt = 0; rt < 4; ++rt)
#pragma unroll
            for (int ct = 0; ct < 2; ++ct)
                acc2[rt][ct] = mfma16(ah[rt], bwc[ct], acc2[rt][ct]);
        __builtin_amdgcn_s_setprio(0);
#pragma unroll
        for (int ct = 0; ct < 2; ++ct) bwc[ct] = bwn[ct];
    }
    __syncthreads();                              // Hs dead; U becomes OutF
    // ---- epilogue 2: OutF[m][c] = acc2 + b2 (f32, swizzled) ----
#pragma unroll
    for (int ct = 0; ct < 2; ++ct) {
        int c = cs + (ct << 4) + li;
        float bb = b2[c];
#pragma unroll
        for (int rt = 0; rt < 4; ++rt)
#pragma unroll
            for (int q = 0; q < 4; ++q) {
                int m = rt * 16 + (lg << 2) + q;
                OutF[m * 256 + (c ^ (((m >> 2) & 3) << 3))] = acc2[rt][ct][q] + bb;
            }
    }
    __syncthreads();
    // ---- coalesced store with residual add (single rounding) ----
    for (int i = tid; i < 64 * 32; i += 512) {
        int r = i >> 5, j = i & 31;
        if (m0 + r >= M) continue;
        unsigned short* xp = x + (size_t)(m0 + r) * 256 + (j << 3);
        short8 xv = *(const short8*)xp;
        int sw = ((r >> 2) & 3) << 3;
        int c0 = (j << 3) ^ sw;
        float4 f0 = *(const float4*)&OutF[r * 256 + c0];
        float4 f1 = *(const float4*)&OutF[r * 256 + c0 + 4];
        short8 o;
        o[0] = (short)f2bf(bf2f((unsigned short)xv[0]) + f0.x);
        o[1] = (short)f2bf(bf2f((unsigned short)xv[1]) + f0.y);
        o[2] = (short)f2bf(bf2f((unsigned short)xv[2]) + f0.z);
        o[3] = (short)f2bf(bf2f((unsigned short)xv[3]) + f0.w);
        o[4] = (short)f2bf(bf2f((unsigned short)xv[4]) + f1.x);
        o[5] = (short)f2bf(bf2f((unsigned short)xv[5]) + f1.y);
        o[6] = (short)f2bf(bf2f((unsigned short)xv[6]) + f1.z);
        o[7] = (short)f2bf(bf2f((unsigned short)xv[7]) + f1.w);
        *(short8*)xp = o;
    }
}

// ---------------- weighted alt segment sums --------------------------------
__global__ void alt_wsum(const float* __restrict__ au, const int* __restrict__ off_a,
                         float* __restrict__ wsum, int V) {
    int v = blockIdx.x * blockDim.x + threadIdx.x;
    if (v >= V) return;
    float s = 0.f;
    for (int r = off_a[v]; r < off_a[v + 1]; r++) s += 1.2f - 0.4f * au[r];
    wsum[v] = s;
}

__global__ __launch_bounds__(256) void alt_weighted_mean_bf(
        const unsigned short* __restrict__ xalt, const float* __restrict__ au,
        const int* __restrict__ off_a, const float* __restrict__ wsum,
        unsigned short* __restrict__ av, int V) {
    __shared__ float red[2048];
    int v = blockIdx.x;
    int t = threadIdx.x;
    int s = off_a[v], e = off_a[v + 1];
    float inv = 1.f / wsum[v];
    int g = t >> 5, c8 = (t & 31) << 3;
    float a[8] = {0.f, 0.f, 0.f, 0.f, 0.f, 0.f, 0.f, 0.f};
    for (int r = s + g; r < e; r += 8) {
        float w = (1.2f - 0.4f * au[r]) * inv;
        short8 vv = *(const short8*)(xalt + (size_t)r * 256 + c8);
#pragma unroll
        for (int k = 0; k < 8; k++) a[k] += bf2f((unsigned short)vv[k]) * w;
    }
#pragma unroll
    for (int k = 0; k < 8; k++) red[g * 256 + c8 + k] = a[k];
    __syncthreads();
    float acc = red[t];
#pragma unroll
    for (int g2 = 1; g2 < 8; g2++) acc += red[g2 * 256 + t];
    av[(size_t)v * 256 + t] = f2bf(acc);
}

// ---------------------------------------------------------------------------
extern "C" void kernel_launch(void* const* d_in, const int* in_sizes, int n_in,
                              void* d_out, int out_size, void* d_ws, size_t ws_size,
                              hipStream_t stream) {
    const float* reads = (const float*)d_in[0];
    const float* info2d = (const float*)d_in[1];
    const float* oh = (const float*)d_in[2];
    const float* au = (const float*)d_in[3];
    const int* ref_counts = (const int*)d_in[4];
    const int* alt_counts = (const int*)d_in[5];
    const float* rw1 = (const float*)d_in[6];
    const float* rb1 = (const float*)d_in[7];
    const float* rw2 = (const float*)d_in[8];
    const float* rb2 = (const float*)d_in[9];
    const float* iw1 = (const float*)d_in[10];
    const float* ib1 = (const float*)d_in[11];
    const float* iw2 = (const float*)d_in[12];
    const float* ib2 = (const float*)d_in[13];
    const float* cw = (const float*)d_in[14];
    const float* cb = (const float*)d_in[15];
    const float* sw = (const float*)d_in[16];
    const float* sb = (const float*)d_in[17];
    const float* blk_w1 = (const float*)d_in[18];
    const float* blk_b1 = (const float*)d_in[19];
    const float* blk_wg = (const float*)d_in[20];
    const float* blk_bg = (const float*)d_in[21];
    const float* blk_w2 = (const float*)d_in[22];
    const float* blk_b2 = (const float*)d_in[23];
    const float* agg_w1 = (const float*)d_in[24];
    const float* agg_b1 = (const float*)d_in[25];
    const float* agg_w2 = (const float*)d_in[26];
    const float* agg_b2 = (const float*)d_in[27];

    const int R = in_sizes[0] / 24;
    const int TA = in_sizes[3];
    const int TR = R - TA;
    const int V = in_sizes[4];

    size_t p = 0;
    auto carve = [&](size_t bytes) -> void* {
        void* q = (char*)d_ws + p;
        p = (p + bytes + 255) & ~(size_t)255;
        return q;
    };
    // persistent
    int* off_r = (int*)carve((V + 1) * sizeof(int));
    int* off_a = (int*)carve((V + 1) * sizeof(int));
    int* rid_r = (int*)carve((size_t)TR * sizeof(int));
    int* rid_a = (int*)carve((size_t)TA * sizeof(int));
    unsigned short* isv = (unsigned short*)carve((size_t)V * 128 * 2);
    unsigned short* xref = (unsigned short*)carve((size_t)TR * 256 * 2);
    unsigned short* xalt = (unsigned short*)carve((size_t)TA * 256 * 2);
    unsigned short* W1t0 = (unsigned short*)carve((size_t)512 * 256 * 2);
    unsigned short* W1t1 = (unsigned short*)carve((size_t)512 * 256 * 2);
    unsigned short* Wgt0 = (unsigned short*)carve((size_t)512 * 256 * 2);
    unsigned short* Wgt1 = (unsigned short*)carve((size_t)512 * 256 * 2);
    unsigned short* W2t0 = (unsigned short*)carve((size_t)256 * 512 * 2);
    unsigned short* W2t1 = (unsigned short*)carve((size_t)256 * 512 * 2);
    unsigned short* RW1t = (unsigned short*)carve((size_t)128 * 32 * 2);
    unsigned short* RW2t = (unsigned short*)carve((size_t)128 * 128 * 2);
    unsigned short* AG1t = (unsigned short*)carve((size_t)256 * 256 * 2);
    unsigned short* AG2t = (unsigned short*)carve((size_t)128 * 256 * 2);
    float* wsum = (float*)carve((size_t)V * sizeof(float));
    // union A: read path temporaries
    size_t mark = p;
    unsigned short* reads_bf = (unsigned short*)carve((size_t)R * 32 * 2);
    unsigned short* h1 = (unsigned short*)carve((size_t)R * 128 * 2);
    size_t endA = p;
    // union B: block loop / aggregation
    p = mark;
    unsigned short* m2 = (unsigned short*)carve((size_t)2 * V * 256 * 2);   // [alt;ref] means
    float* gate2 = (float*)carve((size_t)2 * V * 512 * sizeof(float));      // [gate_r;gate_a]
    unsigned short* avb_bf = (unsigned short*)carve((size_t)V * 256 * 2);
    unsigned short* aggh_bf = (unsigned short*)carve((size_t)V * 256 * 2);
    if (endA > p) p = endA;
    (void)ws_size; (void)n_in; (void)out_size;

    // ---- offsets / ids ----
    scan_counts<<<1, 256, 0, stream>>>(ref_counts, off_r, V);
    scan_counts<<<1, 256, 0, stream>>>(alt_counts, off_a, V);
    fill_ids<<<(2 * V + 255) / 256, 256, 0, stream>>>(off_r, rid_r, off_a, rid_a, V);

    // ---- weight transposes ----
    auto T = [&](const float* src, unsigned short* dst, int K, int N, int Kp) {
        int tot = N * Kp;
        transpose_bf16<<<(tot + 255) / 256, 256, 0, stream>>>(src, dst, K, N, Kp);
    };
    T(blk_w1, W1t0, 256, 512, 256);
    T(blk_w1 + 256 * 512, W1t1, 256, 512, 256);
    T(blk_wg, Wgt0, 256, 512, 256);
    T(blk_wg + 256 * 512, Wgt1, 256, 512, 256);
    T(blk_w2, W2t0, 512, 256, 512);
    T(blk_w2 + 512 * 256, W2t1, 512, 256, 512);
    T(rw1, RW1t, 24, 128, 32);
    T(rw2, RW2t, 128, 128, 128);
    T(agg_w1, AG1t, 256, 256, 256);
    T(agg_w2, AG2t, 256, 128, 256);

    // ---- read MLP -> x[:,0:128] (bf16) ----
    reads_to_bf<<<(R * 32 + 255) / 256, 256, 0, stream>>>(reads, reads_bf, R);
    {
        dim3 g1((R + 63) / 64, 2);
        gemm_bf16<1><<<g1, 256, 64 * 32 * 2, stream>>>(reads_bf, RW1t, rb1, h1, nullptr,
                                                       R, 32, 3, 128, 0);
        gemm_bf16<3><<<g1, 256, 64 * 128 * 2, stream>>>(h1, RW2t, rb2, xref, xalt,
                                                        R, 128, 15, 256, TR);
    }

    // ---- variant embeddings -> x[:,128:256] (bf16) ----
    variant_embed<<<V, 128, 0, stream>>>(info2d, oh, iw1, ib1, iw2, ib2, cw, cb, sw, sb, isv, V);
    long gtot = (long)R * 16;
    gather_isv_bf<<<(int)((gtot + 255) / 256), 256, 0, stream>>>(
        (const uint4*)isv, rid_r, rid_a, (uint4*)xref, (uint4*)xalt, TR, TA);

    // ---- 2 gated residual blocks ----
    const int ntr = (TR + 63) / 64, nta = (TA + 63) / 64;
    for (int it = 0; it < 2; ++it) {
        const unsigned short* W1t = it ? W1t1 : W1t0;
        const unsigned short* Wgt = it ? Wgt1 : Wgt0;
        const unsigned short* W2t = it ? W2t1 : W2t0;
        const float* B1 = blk_b1 + (size_t)it * 512;
        const float* Bg = blk_bg + (size_t)it * 512;
        const float* B2 = blk_b2 + (size_t)it * 256;

        seg_mean_bf<<<2 * V, 256, 0, stream>>>(xref, off_r, xalt, off_a, m2, V);
        // stacked gate GEMM: rows [0,V)=gate_r (from alt means), [V,2V)=gate_a
        dim3 gg(2 * V / 64, 8);
        gemm_bf16<2><<<gg, 256, 64 * 256 * 2, stream>>>(m2, Wgt, Bg, gate2, nullptr,
                                                        2 * V, 256, 15, 512, 0);
        fused_block<<<ntr + nta, 512, 0, stream>>>(xref, xalt, W1t, W2t, B1, B2,
                                                   gate2, gate2 + (size_t)V * 512,
                                                   rid_r, rid_a, TR, TA, ntr);
    }

    // ---- weighted alt means + agg MLP ----
    alt_wsum<<<(V + 255) / 256, 256, 0, stream>>>(au, off_a, wsum, V);
    alt_weighted_mean_bf<<<V, 256, 0, stream>>>(xalt, au, off_a, wsum, avb_bf, V);
    {
        dim3 ga(V / 64, 4);
        gemm_bf16<1><<<ga, 256, 64 * 256 * 2, stream>>>(avb_bf, AG1t, agg_b1, aggh_bf, nullptr,
                                                        V, 256, 15, 256, 0);
        dim3 go(V / 64, 2);
        gemm_bf16<0><<<go, 256, 64 * 256 * 2, stream>>>(aggh_bf, AG2t, agg_b2, d_out, nullptr,
                                                        V, 256, 15, 128, 0);
    }
}